// Round 5
// baseline (153.625 us; speedup 1.0000x reference)
//
#include <hip/hip_runtime.h>
#include <stdint.h>

// DiagonalSSM: out = (scan_t tanh(exp(-A)*state + (x@Bw^T)_t)) @ Wo^T + bo
// B=8, S=2048, Din=Dstate=Dout=1024, fp32 in/out.
//
// Pipeline:
//   cvt x,Bw -> bf16; cvt Wo -> bf16 * (-2); dkc[n] = C2*exp(-min(A,10));
//   bias2[o] = bo[o] + rowsum(Wo)[o]
//   GEMM1 (256^2 tile, BK=64, 2-buf counted-vmcnt, read/MFMA interleave):
//        c'' = C2*(x@Bw^T)+dkc -> d_out
//   scan (r-space, time-chunked w/ 384-step warmup, 2 chains/thread) -> bf16 ws
//   GEMM2: out = r @ (-2*Wo)^T + bias2 -> d_out

typedef __attribute__((ext_vector_type(8))) short bf16x8;
typedef __attribute__((ext_vector_type(4))) float f32x4;
typedef __attribute__((ext_vector_type(8))) unsigned short u16x8;

#define C2F 2.88539008177792681472f  // 2*log2(e)
#define LOG2E 1.44269504088896340736f

static __device__ __forceinline__ unsigned short f2b(float f) {
  unsigned u = __builtin_bit_cast(unsigned, f);
  unsigned r = 0x7FFFu + ((u >> 16) & 1u);  // round-to-nearest-even
  return (unsigned short)((u + r) >> 16);
}

// global -> LDS async copy, 16B per lane; LDS dest = wave-uniform base + lane*16.
static __device__ __forceinline__ void gload_lds16(const void* g, void* l) {
  __builtin_amdgcn_global_load_lds(
      (const __attribute__((address_space(1))) void*)(uintptr_t)g,
      (__attribute__((address_space(3))) void*)(unsigned)(uintptr_t)l,
      16, 0, 0);
}

// ---------------- f32 -> bf16 convert (with scale), 8 elems/thread ----------------
__global__ __launch_bounds__(256) void cvt_f32_bf16(const float* __restrict__ in,
                                                    unsigned short* __restrict__ out,
                                                    float scale, int n8) {
  int i = blockIdx.x * 256 + threadIdx.x;
  if (i >= n8) return;
  const float4* p = (const float4*)in;
  float4 v0 = p[2 * (size_t)i];
  float4 v1 = p[2 * (size_t)i + 1];
  u16x8 o;
  o[0] = f2b(v0.x * scale); o[1] = f2b(v0.y * scale);
  o[2] = f2b(v0.z * scale); o[3] = f2b(v0.w * scale);
  o[4] = f2b(v1.x * scale); o[5] = f2b(v1.y * scale);
  o[6] = f2b(v1.z * scale); o[7] = f2b(v1.w * scale);
  *(u16x8*)(out + 8 * (size_t)i) = o;
}

// ---------------- dkc[n] = C2 * exp(-min(A[n],10)) ----------------
__global__ __launch_bounds__(256) void dkc_kernel(const float* __restrict__ Av,
                                                  float* __restrict__ dkc, int n) {
  int i = blockIdx.x * 256 + threadIdx.x;
  if (i >= n) return;
  float a = fminf(Av[i], 10.0f);
  dkc[i] = C2F * __builtin_amdgcn_exp2f(-a * LOG2E);
}

// ---------------- bias2[o] = bo[o] + sum_n Wo[o][n] ----------------
__global__ __launch_bounds__(256) void bias2_kernel(const float* __restrict__ Wo,
                                                    const float* __restrict__ bo,
                                                    float* __restrict__ bias2) {
  const int o = blockIdx.x * 4 + (threadIdx.x >> 6);
  const int lane = threadIdx.x & 63;
  const float4* row = (const float4*)(Wo + (size_t)o * 1024);
  float s = 0.0f;
#pragma unroll
  for (int k = 0; k < 4; ++k) {
    float4 v = row[lane + k * 64];
    s += v.x + v.y + v.z + v.w;
  }
#pragma unroll
  for (int off = 32; off; off >>= 1) s += __shfl_down(s, off);
  if (lane == 0) bias2[o] = s + bo[o];
}

// ======== 256x256-tile GEMM, C[M][N] = A[M][K] @ B[N][K]^T, epilogue-fused ========
// 8 waves (2m x 4n), BK=64 (2 kslices of 32), 2-deep LDS double buffer:
//   lds[buf][op][kslice][16KB], 16KB block = 256 rows x 32 cols bf16, T2-swizzled:
//   byte(row,chunk) = (row>>1)*128 + ((((row&1)<<2)+chunk) ^ ((row>>1)&7))*16
//   gload_lds dest LINEAR, per-lane GLOBAL source inverse-permuted (rule #21).
// Schedule per K-tile t: STAGE(t+1)[8 gl/thr]; vmcnt(8); barrier;
//   R1(8 ds_read) R2(4) M0(16 mfma) R3(8) M1(16) R4(4) M2(16) M3(16); barrier.
//   Read batches issued ahead of MFMA clusters in program order -> compiler's
//   counted lgkmcnt overlaps LDS pipe with MFMA pipe (T3+T4). T5 setprio on clusters.
// MODE 0: C = acc*C2 + bv[col]   MODE 1: C = acc + bv[col]
template <int MODE>
__global__ __launch_bounds__(512, 2) void gemm256(const unsigned short* __restrict__ A,
                                                  const unsigned short* __restrict__ B,
                                                  float* __restrict__ C,
                                                  const float* __restrict__ bv,
                                                  int M, int N, int K) {
  __shared__ char lds[2][2][2][16384];  // [buf][op][kslice][16KB] = 128 KiB
  const int tid = threadIdx.x;
  const int wave = tid >> 6, lane = tid & 63;
  const int wr = wave >> 2, wc = wave & 3;

  // T1: XCD-chunked block mapping (grid multiple of 8; bijective).
  const int nbn = N >> 8;
  const int per = gridDim.x >> 3;
  const int tilei = (blockIdx.x & 7) * per + (blockIdx.x >> 3);
  const int m0 = (tilei / nbn) << 8;
  const int n0 = (tilei % nbn) << 8;

  // Staging: per issue i, linear LDS offset o = i*8192 + wave*1024 + lane*16
  // within a 16KB block. Invert swizzle -> (row, chunk) to fetch from global.
  int soff[2];
#pragma unroll
  for (int i = 0; i < 2; ++i) {
    int o = i * 8192 + wave * 1024 + lane * 16;
    int rp = o >> 7;
    int p = ((o >> 4) & 7) ^ (rp & 7);
    int row = rp * 2 + (p >> 2);
    int chunk = p & 3;
    soff[i] = row * K + chunk * 8;  // element offset within [256 rows][32 cols] block
  }
  const unsigned short* Abase = A + (size_t)m0 * K;
  const unsigned short* Bbase = B + (size_t)n0 * K;

#define STAGE(T_)                                                                 \
  {                                                                               \
    const int _buf = (T_) & 1;                                                    \
    const int _k0 = (T_) * 64;                                                    \
    _Pragma("unroll") for (int ks = 0; ks < 2; ++ks)                              \
      _Pragma("unroll") for (int i = 0; i < 2; ++i) {                             \
        gload_lds16(Abase + _k0 + ks * 32 + soff[i],                              \
                    &lds[_buf][0][ks][i * 8192 + wave * 1024]);                   \
        gload_lds16(Bbase + _k0 + ks * 32 + soff[i],                              \
                    &lds[_buf][1][ks][i * 8192 + wave * 1024]);                   \
      }                                                                           \
  }

  // Swizzled read bases (frag offsets are +mf*1024 / +nf*1024: (row>>1)&7 is
  // invariant under row += 16).
  const int l15 = lane & 15, ck = lane >> 4;
  const int ra = wr * 128 + l15;
  const int rb = wc * 64 + l15;
  const int baseA = (ra >> 1) * 128 + ((((ra & 1) << 2) + ck) ^ ((ra >> 1) & 7)) * 16;
  const int baseB = (rb >> 1) * 128 + ((((rb & 1) << 2) + ck) ^ ((rb >> 1) & 7)) * 16;

  f32x4 acc[8][4] = {};

#define MFMA_(a_, b_, c_) __builtin_amdgcn_mfma_f32_16x16x32_bf16(a_, b_, c_, 0, 0, 0)

  // Interleaved compute of buffer BUF_: read batches ahead of MFMA clusters.
#define COMPUTE(BUF_)                                                             \
  {                                                                               \
    const char* paA0 = &lds[BUF_][0][0][baseA];                                   \
    const char* paA1 = &lds[BUF_][0][1][baseA];                                   \
    const char* pbB0 = &lds[BUF_][1][0][baseB];                                   \
    const char* pbB1 = &lds[BUF_][1][1][baseB];                                   \
    bf16x8 b0[4], b1[4], alo[4], ahi[4], clo[4], chi[4];                          \
    _Pragma("unroll") for (int nf = 0; nf < 4; ++nf)                              \
        b0[nf] = *(const bf16x8*)(pbB0 + nf * 1024);                              \
    _Pragma("unroll") for (int mf = 0; mf < 4; ++mf)                              \
        alo[mf] = *(const bf16x8*)(paA0 + mf * 1024);                             \
    _Pragma("unroll") for (int mf = 0; mf < 4; ++mf)                              \
        ahi[mf] = *(const bf16x8*)(paA0 + (mf + 4) * 1024);                       \
    __builtin_amdgcn_s_setprio(1);                                                \
    _Pragma("unroll") for (int mf = 0; mf < 4; ++mf)                              \
      _Pragma("unroll") for (int nf = 0; nf < 4; ++nf)                            \
        acc[mf][nf] = MFMA_(alo[mf], b0[nf], acc[mf][nf]);                        \
    __builtin_amdgcn_s_setprio(0);                                                \
    _Pragma("unroll") for (int nf = 0; nf < 4; ++nf)                              \
        b1[nf] = *(const bf16x8*)(pbB1 + nf * 1024);                              \
    _Pragma("unroll") for (int mf = 0; mf < 4; ++mf)                              \
        clo[mf] = *(const bf16x8*)(paA1 + mf * 1024);                             \
    __builtin_amdgcn_s_setprio(1);                                                \
    _Pragma("unroll") for (int mf = 0; mf < 4; ++mf)                              \
      _Pragma("unroll") for (int nf = 0; nf < 4; ++nf)                            \
        acc[mf + 4][nf] = MFMA_(ahi[mf], b0[nf], acc[mf + 4][nf]);                \
    __builtin_amdgcn_s_setprio(0);                                                \
    _Pragma("unroll") for (int mf = 0; mf < 4; ++mf)                              \
        chi[mf] = *(const bf16x8*)(paA1 + (mf + 4) * 1024);                       \
    __builtin_amdgcn_s_setprio(1);                                                \
    _Pragma("unroll") for (int mf = 0; mf < 4; ++mf)                              \
      _Pragma("unroll") for (int nf = 0; nf < 4; ++nf)                            \
        acc[mf][nf] = MFMA_(clo[mf], b1[nf], acc[mf][nf]);                        \
    _Pragma("unroll") for (int mf = 0; mf < 4; ++mf)                              \
      _Pragma("unroll") for (int nf = 0; nf < 4; ++nf)                            \
        acc[mf + 4][nf] = MFMA_(chi[mf], b1[nf], acc[mf + 4][nf]);                \
    __builtin_amdgcn_s_setprio(0);                                                \
  }

#define WAIT8 asm volatile("s_waitcnt vmcnt(8)" ::: "memory")
#define WAIT0 asm volatile("s_waitcnt vmcnt(0)" ::: "memory")
#define BAR __builtin_amdgcn_s_barrier()

  const int T = K / 64;  // 16 at K=1024; requires T even, >= 4

  STAGE(0);
  for (int t = 0; t < T - 2; t += 2) {
    STAGE(t + 1); WAIT8; BAR; COMPUTE(0); BAR;
    STAGE(t + 2); WAIT8; BAR; COMPUTE(1); BAR;
  }
  STAGE(T - 1); WAIT8; BAR; COMPUTE(0); BAR;
  WAIT0;        BAR; COMPUTE(1); BAR;

#undef COMPUTE
#undef STAGE
#undef WAIT8
#undef WAIT0
#undef BAR

  // Epilogue. C/D layout (m89-verified): col = lane&15, row = (lane>>4)*4 + reg
  const int cr = (lane >> 4) * 4;
  const int cc = lane & 15;
#pragma unroll
  for (int nf = 0; nf < 4; ++nf) {
    const int gc = n0 + wc * 64 + nf * 16 + cc;
    const float b = bv[gc];
#pragma unroll
    for (int mf = 0; mf < 8; ++mf) {
      const size_t base = (size_t)(m0 + wr * 128 + mf * 16 + cr) * N + gc;
#pragma unroll
      for (int r = 0; r < 4; ++r) {
        float v = MODE == 0 ? fmaf(acc[mf][nf][r], C2F, b) : (acc[mf][nf][r] + b);
        C[base + (size_t)r * N] = v;
      }
    }
  }
}

// ---------------- time-chunked scan, r-space, 2 adjacent channels/thread ----------------
// S split into 8 chunks of 256. Chunk c starts from state=0 at t = max(0, c*256-384):
// warmup contracts the wrong-init error by prod(dec*sech^2) ~ e^{-13} over 384 steps.
// Thread owns channels (2p, 2p+1): float2 loads, packed dword bf16 stores (cvt_pk).
__global__ __launch_bounds__(256) void scan_kernel(const float* __restrict__ Bx,
                                                   const float* __restrict__ Av,
                                                   unsigned short* __restrict__ h) {
  constexpr int S = 2048, D = 1024, CHUNK = 256, W = 384;
  const int bid = blockIdx.x;
  const int half = bid & 1;
  const int chunk = (bid >> 1) & 7;
  const int b = bid >> 4;
  const int p = half * 256 + threadIdx.x;  // 0..511
  const unsigned n0 = 2u * p;

  const float2 av = *(const float2*)(Av + n0);
  const float m2dk0 = -2.0f * C2F * __builtin_amdgcn_exp2f(-fminf(av.x, 10.0f) * LOG2E);
  const float m2dk1 = -2.0f * C2F * __builtin_amdgcn_exp2f(-fminf(av.y, 10.0f) * LOG2E);

  const unsigned base = (unsigned)b * (S * D) + n0;
  const int t_store0 = chunk * CHUNK;
  const int t_start = (chunk * CHUNK - W) < 0 ? 0 : (chunk * CHUNK - W);
  const int t_end = t_store0 + CHUNK;

  float2 A[8], Bf[8];
#pragma unroll
  for (int j = 0; j < 8; ++j) A[j] = *(const float2*)(Bx + base + (unsigned)(t_start + j) * D);
#pragma unroll
  for (int j = 0; j < 8; ++j) Bf[j] = *(const float2*)(Bx + base + (unsigned)(t_start + 8 + j) * D);

  float r0 = 0.5f, r1 = 0.5f;  // s = 1-2r = 0

#define STEP2(CV)                                         \
  {                                                       \
    float w0 = fmaf(m2dk0, r0, (CV).x);                   \
    float w1 = fmaf(m2dk1, r1, (CV).y);                   \
    float e0 = __builtin_amdgcn_exp2f(w0);                \
    float e1 = __builtin_amdgcn_exp2f(w1);                \
    r0 = __builtin_amdgcn_rcpf(e0 + 1.0f);                \
    r1 = __builtin_amdgcn_rcpf(e1 + 1.0f);                \
  }

#define STORE2(T_)                                                        \
  {                                                                       \
    unsigned pk;                                                          \
    asm("v_cvt_pk_bf16_f32 %0, %1, %2" : "=v"(pk) : "v"(r0), "v"(r1));    \
    *(unsigned*)(h + base + (unsigned)(T_) * D) = pk;                     \
  }

  // warmup (no stores); lengths are multiples of 16
  for (int t0 = t_start; t0 < t_store0; t0 += 16) {
#pragma unroll
    for (int j = 0; j < 8; ++j) STEP2(A[j]);
#pragma unroll
    for (int j = 0; j < 8; ++j) A[j] = *(const float2*)(Bx + base + (unsigned)(t0 + 16 + j) * D);
#pragma unroll
    for (int j = 0; j < 8; ++j) STEP2(Bf[j]);
#pragma unroll
    for (int j = 0; j < 8; ++j) Bf[j] = *(const float2*)(Bx + base + (unsigned)(t0 + 24 + j) * D);
  }
  // stored region
  for (int t0 = t_store0; t0 < t_end; t0 += 16) {
#pragma unroll
    for (int j = 0; j < 8; ++j) { STEP2(A[j]); STORE2(t0 + j); }
    if (t0 + 16 < t_end) {
#pragma unroll
      for (int j = 0; j < 8; ++j) A[j] = *(const float2*)(Bx + base + (unsigned)(t0 + 16 + j) * D);
    }
#pragma unroll
    for (int j = 0; j < 8; ++j) { STEP2(Bf[j]); STORE2(t0 + 8 + j); }
    if (t0 + 24 < t_end) {
#pragma unroll
      for (int j = 0; j < 8; ++j) Bf[j] = *(const float2*)(Bx + base + (unsigned)(t0 + 24 + j) * D);
    }
  }
#undef STEP2
#undef STORE2
}

extern "C" void kernel_launch(void* const* d_in, const int* in_sizes, int n_in,
                              void* d_out, int out_size, void* d_ws, size_t ws_size,
                              hipStream_t stream) {
  const float* x  = (const float*)d_in[0];
  const float* Av = (const float*)d_in[1];
  const float* Bw = (const float*)d_in[2];
  const float* Wo = (const float*)d_in[3];
  const float* bo = (const float*)d_in[4];
  float* out = (float*)d_out;

  const int Bsz = 8, S = 2048, Din = 1024, Dst = 1024, Dout = 1024;
  const int M = Bsz * S;  // 16384

  char* ws = (char*)d_ws;
  unsigned short* x_bf  = (unsigned short*)ws;
  unsigned short* r_bf  = (unsigned short*)(ws + (size_t)M * Din * 2);
  unsigned short* Bw_bf = (unsigned short*)(ws + (size_t)M * Din * 4);
  unsigned short* Wo_bf = (unsigned short*)(ws + (size_t)M * Din * 4 + (size_t)Dst * Din * 2);
  float* dkc   = (float*)(ws + (size_t)M * Din * 4 + (size_t)Dst * Din * 4);
  float* bias2 = dkc + Dst;

  float* Bx = out;  // d_out doubles as pre-scan scratch (c'' values)

  { int n8 = M * Din / 8;
    cvt_f32_bf16<<<(n8 + 255) / 256, 256, 0, stream>>>(x, x_bf, 1.0f, n8); }
  { int n8 = Dst * Din / 8;
    cvt_f32_bf16<<<(n8 + 255) / 256, 256, 0, stream>>>(Bw, Bw_bf, 1.0f, n8); }
  { int n8 = Dout * Dst / 8;
    cvt_f32_bf16<<<(n8 + 255) / 256, 256, 0, stream>>>(Wo, Wo_bf, -2.0f, n8); }
  dkc_kernel<<<4, 256, 0, stream>>>(Av, dkc, Dst);
  bias2_kernel<<<Dout / 4, 256, 0, stream>>>(Wo, bo, bias2);

  gemm256<0><<<dim3((M / 256) * (Dst / 256)), 512, 0, stream>>>(x_bf, Bw_bf, Bx, dkc, M, Dst, Din);
  scan_kernel<<<dim3(128), 256, 0, stream>>>(Bx, Av, r_bf);
  gemm256<1><<<dim3((M / 256) * (Dout / 256)), 512, 0, stream>>>(r_bf, Wo_bf, out, bias2, M, Dout, Dst);
}

// Round 6
// 146.578 us; speedup vs baseline: 1.0481x; 1.0481x over previous
//
#include <hip/hip_runtime.h>
#include <stdint.h>

// DiagonalSSM: out = (scan_t tanh(exp(-A)*state + (x@Bw^T)_t)) @ Wo^T + bo
// B=8, S=2048, Din=Dstate=Dout=1024, fp32 in/out.
//
// Pipeline:
//   cvt x,Bw -> bf16; cvt Wo -> bf16 * (-2); dkc[n] = C2*exp(-min(A,10));
//   bias2[o] = bo[o] + rowsum(Wo)[o]
//   GEMM1 (256^2, BK=64, 4-phase-per-tile m201-style schedule):
//        c'' = C2*(x@Bw^T)+dkc -> d_out
//   scan (r-space, time-chunked w/ 384-step warmup, 2 chains/thread) -> bf16 ws
//   GEMM2: out = r @ (-2*Wo)^T + bias2 -> d_out

typedef __attribute__((ext_vector_type(8))) short bf16x8;
typedef __attribute__((ext_vector_type(4))) float f32x4;
typedef __attribute__((ext_vector_type(8))) unsigned short u16x8;

#define C2F 2.88539008177792681472f  // 2*log2(e)
#define LOG2E 1.44269504088896340736f

static __device__ __forceinline__ unsigned short f2b(float f) {
  unsigned u = __builtin_bit_cast(unsigned, f);
  unsigned r = 0x7FFFu + ((u >> 16) & 1u);  // round-to-nearest-even
  return (unsigned short)((u + r) >> 16);
}

// global -> LDS async copy, 16B per lane; LDS dest = wave-uniform base + lane*16.
static __device__ __forceinline__ void gload_lds16(const void* g, void* l) {
  __builtin_amdgcn_global_load_lds(
      (const __attribute__((address_space(1))) void*)(uintptr_t)g,
      (__attribute__((address_space(3))) void*)(unsigned)(uintptr_t)l,
      16, 0, 0);
}

// ---------------- f32 -> bf16 convert (with scale), 8 elems/thread ----------------
__global__ __launch_bounds__(256) void cvt_f32_bf16(const float* __restrict__ in,
                                                    unsigned short* __restrict__ out,
                                                    float scale, int n8) {
  int i = blockIdx.x * 256 + threadIdx.x;
  if (i >= n8) return;
  const float4* p = (const float4*)in;
  float4 v0 = p[2 * (size_t)i];
  float4 v1 = p[2 * (size_t)i + 1];
  u16x8 o;
  o[0] = f2b(v0.x * scale); o[1] = f2b(v0.y * scale);
  o[2] = f2b(v0.z * scale); o[3] = f2b(v0.w * scale);
  o[4] = f2b(v1.x * scale); o[5] = f2b(v1.y * scale);
  o[6] = f2b(v1.z * scale); o[7] = f2b(v1.w * scale);
  *(u16x8*)(out + 8 * (size_t)i) = o;
}

// ---------------- dkc[n] = C2 * exp(-min(A[n],10)) ----------------
__global__ __launch_bounds__(256) void dkc_kernel(const float* __restrict__ Av,
                                                  float* __restrict__ dkc, int n) {
  int i = blockIdx.x * 256 + threadIdx.x;
  if (i >= n) return;
  float a = fminf(Av[i], 10.0f);
  dkc[i] = C2F * __builtin_amdgcn_exp2f(-a * LOG2E);
}

// ---------------- bias2[o] = bo[o] + sum_n Wo[o][n] ----------------
__global__ __launch_bounds__(256) void bias2_kernel(const float* __restrict__ Wo,
                                                    const float* __restrict__ bo,
                                                    float* __restrict__ bias2) {
  const int o = blockIdx.x * 4 + (threadIdx.x >> 6);
  const int lane = threadIdx.x & 63;
  const float4* row = (const float4*)(Wo + (size_t)o * 1024);
  float s = 0.0f;
#pragma unroll
  for (int k = 0; k < 4; ++k) {
    float4 v = row[lane + k * 64];
    s += v.x + v.y + v.z + v.w;
  }
#pragma unroll
  for (int off = 32; off; off >>= 1) s += __shfl_down(s, off);
  if (lane == 0) bias2[o] = s + bo[o];
}

// ======== 256x256-tile GEMM, C[M][N] = A[M][K] @ B[N][K]^T, epilogue-fused ========
// 8 waves (2m x 4n), BK=64, 2-deep LDS double buffer, 4 PHASES PER K-TILE (m201
// discipline): each phase = {ds_read this phase's quadrant frags || stage gloads
// -> barrier -> lgkmcnt(0)+sched_barrier -> setprio(1) 16 MFMA setprio(0) ->
// barrier}. Quadrant order (0,0),(0,1),(1,1),(1,0): B0 regs live whole tile,
// reads/phase = [12,4,8,0]. Stage of tile t+1 issued in P1(A)/P2(B); single
// vmcnt(0) folded into P4's closing barrier (>=2 phases of HBM-latency slack).
// LDS swizzle (T2, rule #21, 0-conflict verified):
//   byte(row,chunk) = (row>>1)*128 + ((((row&1)<<2)+chunk) ^ ((row>>1)&7))*16
// MODE 0: C = acc*C2 + bv[col]   MODE 1: C = acc + bv[col]
template <int MODE>
__global__ __launch_bounds__(512, 2) void gemm256(const unsigned short* __restrict__ A,
                                                  const unsigned short* __restrict__ B,
                                                  float* __restrict__ C,
                                                  const float* __restrict__ bv,
                                                  int M, int N, int K) {
  __shared__ char lds[2][2][2][16384];  // [dbuf][op][kslice][16KB] = 128 KiB
  const int tid = threadIdx.x;
  const int wave = tid >> 6, lane = tid & 63;
  const int wr = wave >> 2, wc = wave & 3;

  // T1: XCD-chunked block mapping (grid multiple of 8; bijective).
  const int nbn = N >> 8;
  const int per = gridDim.x >> 3;
  const int tilei = (blockIdx.x & 7) * per + (blockIdx.x >> 3);
  const int m0 = (tilei / nbn) << 8;
  const int n0 = (tilei % nbn) << 8;

  // Staging: per issue i, linear LDS offset o = i*8192 + wave*1024 + lane*16
  // within a 16KB block. Invert swizzle -> (row, chunk) to fetch from global.
  int soff[2];
#pragma unroll
  for (int i = 0; i < 2; ++i) {
    int o = i * 8192 + wave * 1024 + lane * 16;
    int rp = o >> 7;
    int p = ((o >> 4) & 7) ^ (rp & 7);
    int row = rp * 2 + (p >> 2);
    int chunk = p & 3;
    soff[i] = row * K + chunk * 8;  // element offset within [256 rows][32 cols] block
  }
  const unsigned short* Abase = A + (size_t)m0 * K;
  const unsigned short* Bbase = B + (size_t)n0 * K;

  // stage one operand (OP: 0=A from Abase, 1=B from Bbase) of tile T_ (4 gloads)
#define STAGE_OP(T_, OP, SRC)                                                     \
  {                                                                               \
    const int _b = (T_) & 1;                                                      \
    const int _k0 = (T_) * 64;                                                    \
    _Pragma("unroll") for (int ks = 0; ks < 2; ++ks)                              \
      _Pragma("unroll") for (int i = 0; i < 2; ++i)                               \
        gload_lds16(SRC + _k0 + ks * 32 + soff[i],                                \
                    &lds[_b][OP][ks][i * 8192 + wave * 1024]);                    \
  }

  // Swizzled read bases (frag offsets are +f*1024: (row>>1)&7 invariant mod 16 rows)
  const int l15 = lane & 15, ck = lane >> 4;
  const int ra = wr * 128 + l15;
  const int rb = wc * 64 + l15;
  const int baseA = (ra >> 1) * 128 + ((((ra & 1) << 2) + ck) ^ ((ra >> 1) & 7)) * 16;
  const int baseB = (rb >> 1) * 128 + ((((rb & 1) << 2) + ck) ^ ((rb >> 1) & 7)) * 16;

  f32x4 acc[8][4] = {};
  bf16x8 rA[8], rB0[4], rB1[4];

  // read A-frags for row-half MH of buffer BUF into rA (8 x ds_read_b128)
#define RD_A(BUF, MH)                                                             \
  _Pragma("unroll") for (int mf = 0; mf < 4; ++mf)                                \
    _Pragma("unroll") for (int ks = 0; ks < 2; ++ks)                              \
      rA[mf * 2 + ks] = *(const bf16x8*)(&lds[BUF][0][ks][baseA + ((MH)*4 + mf) * 1024]);

  // read B-frags for col-half NH of buffer BUF into DST (4 x ds_read_b128)
#define RD_B(DST, BUF, NH)                                                        \
  _Pragma("unroll") for (int i = 0; i < 2; ++i)                                   \
    _Pragma("unroll") for (int ks = 0; ks < 2; ++ks)                              \
      DST[i * 2 + ks] = *(const bf16x8*)(&lds[BUF][1][ks][baseB + ((NH)*2 + i) * 1024]);

#define MFMA_(a_, b_, c_) __builtin_amdgcn_mfma_f32_16x16x32_bf16(a_, b_, c_, 0, 0, 0)

  // 16 MFMA: C-quadrant (MH, NH) x K=64, using rA and BREG
#define MM(MH, NH, BREG)                                                          \
  __builtin_amdgcn_s_setprio(1);                                                  \
  _Pragma("unroll") for (int mf = 0; mf < 4; ++mf)                                \
    _Pragma("unroll") for (int i = 0; i < 2; ++i)                                 \
      _Pragma("unroll") for (int ks = 0; ks < 2; ++ks)                            \
        acc[(MH)*4 + mf][(NH)*2 + i] =                                            \
            MFMA_(rA[mf * 2 + ks], BREG[i * 2 + ks], acc[(MH)*4 + mf][(NH)*2 + i]); \
  __builtin_amdgcn_s_setprio(0);

#define BAR __builtin_amdgcn_s_barrier()
#define LGKM0                                                                     \
  do {                                                                            \
    asm volatile("s_waitcnt lgkmcnt(0)" ::: "memory");                            \
    __builtin_amdgcn_sched_barrier(0);                                            \
  } while (0)
#define VM0 asm volatile("s_waitcnt vmcnt(0)" ::: "memory")

  const int T = K / 64;  // 16 at K=1024

  STAGE_OP(0, 0, Abase);
  STAGE_OP(0, 1, Bbase);
  VM0; BAR;

  for (int t = 0; t < T; ++t) {
    const int cur = t & 1;
    const bool st = (t + 1) < T;
    // ---- P1: quadrant (0,0) ----
    RD_B(rB0, cur, 0);
    RD_A(cur, 0);
    if (st) STAGE_OP(t + 1, 0, Abase);
    BAR; LGKM0;
    MM(0, 0, rB0);
    BAR;
    // ---- P2: quadrant (0,1) ----
    RD_B(rB1, cur, 1);
    if (st) STAGE_OP(t + 1, 1, Bbase);
    BAR; LGKM0;
    MM(0, 1, rB1);
    BAR;
    // ---- P3: quadrant (1,1) ----
    RD_A(cur, 1);
    BAR; LGKM0;
    MM(1, 1, rB1);
    BAR;
    // ---- P4: quadrant (1,0), regs all live; tile-boundary stage wait ----
    MM(1, 0, rB0);
    VM0; BAR;
  }

#undef STAGE_OP
#undef RD_A
#undef RD_B
#undef MM
#undef BAR
#undef LGKM0
#undef VM0

  // Epilogue. C/D layout (m89-verified): col = lane&15, row = (lane>>4)*4 + reg
  const int cr = (lane >> 4) * 4;
  const int cc = lane & 15;
#pragma unroll
  for (int nf = 0; nf < 4; ++nf) {
    const int gc = n0 + wc * 64 + nf * 16 + cc;
    const float b = bv[gc];
#pragma unroll
    for (int mf = 0; mf < 8; ++mf) {
      const size_t base = (size_t)(m0 + wr * 128 + mf * 16 + cr) * N + gc;
#pragma unroll
      for (int r = 0; r < 4; ++r) {
        float v = MODE == 0 ? fmaf(acc[mf][nf][r], C2F, b) : (acc[mf][nf][r] + b);
        C[base + (size_t)r * N] = v;
      }
    }
  }
}

// ---------------- time-chunked scan, r-space, 2 adjacent channels/thread ----------------
// S split into 8 chunks of 256. Chunk c starts from state=0 at t = max(0, c*256-384):
// warmup contracts the wrong-init error by prod(dec*sech^2) ~ e^{-13} over 384 steps.
// Thread owns channels (2p, 2p+1): float2 loads, packed dword bf16 stores (cvt_pk).
__global__ __launch_bounds__(256) void scan_kernel(const float* __restrict__ Bx,
                                                   const float* __restrict__ Av,
                                                   unsigned short* __restrict__ h) {
  constexpr int S = 2048, D = 1024, CHUNK = 256, W = 384;
  const int bid = blockIdx.x;
  const int half = bid & 1;
  const int chunk = (bid >> 1) & 7;
  const int b = bid >> 4;
  const int p = half * 256 + threadIdx.x;  // 0..511
  const unsigned n0 = 2u * p;

  const float2 av = *(const float2*)(Av + n0);
  const float m2dk0 = -2.0f * C2F * __builtin_amdgcn_exp2f(-fminf(av.x, 10.0f) * LOG2E);
  const float m2dk1 = -2.0f * C2F * __builtin_amdgcn_exp2f(-fminf(av.y, 10.0f) * LOG2E);

  const unsigned base = (unsigned)b * (S * D) + n0;
  const int t_store0 = chunk * CHUNK;
  const int t_start = (chunk * CHUNK - W) < 0 ? 0 : (chunk * CHUNK - W);
  const int t_end = t_store0 + CHUNK;

  float2 A[8], Bf[8];
#pragma unroll
  for (int j = 0; j < 8; ++j) A[j] = *(const float2*)(Bx + base + (unsigned)(t_start + j) * D);
#pragma unroll
  for (int j = 0; j < 8; ++j) Bf[j] = *(const float2*)(Bx + base + (unsigned)(t_start + 8 + j) * D);

  float r0 = 0.5f, r1 = 0.5f;  // s = 1-2r = 0

#define STEP2(CV)                                         \
  {                                                       \
    float w0 = fmaf(m2dk0, r0, (CV).x);                   \
    float w1 = fmaf(m2dk1, r1, (CV).y);                   \
    float e0 = __builtin_amdgcn_exp2f(w0);                \
    float e1 = __builtin_amdgcn_exp2f(w1);                \
    r0 = __builtin_amdgcn_rcpf(e0 + 1.0f);                \
    r1 = __builtin_amdgcn_rcpf(e1 + 1.0f);                \
  }

#define STORE2(T_)                                                        \
  {                                                                       \
    unsigned pk;                                                          \
    asm("v_cvt_pk_bf16_f32 %0, %1, %2" : "=v"(pk) : "v"(r0), "v"(r1));    \
    *(unsigned*)(h + base + (unsigned)(T_) * D) = pk;                     \
  }

  // warmup (no stores); lengths are multiples of 16
  for (int t0 = t_start; t0 < t_store0; t0 += 16) {
#pragma unroll
    for (int j = 0; j < 8; ++j) STEP2(A[j]);
#pragma unroll
    for (int j = 0; j < 8; ++j) A[j] = *(const float2*)(Bx + base + (unsigned)(t0 + 16 + j) * D);
#pragma unroll
    for (int j = 0; j < 8; ++j) STEP2(Bf[j]);
#pragma unroll
    for (int j = 0; j < 8; ++j) Bf[j] = *(const float2*)(Bx + base + (unsigned)(t0 + 24 + j) * D);
  }
  // stored region
  for (int t0 = t_store0; t0 < t_end; t0 += 16) {
#pragma unroll
    for (int j = 0; j < 8; ++j) { STEP2(A[j]); STORE2(t0 + j); }
    if (t0 + 16 < t_end) {
#pragma unroll
      for (int j = 0; j < 8; ++j) A[j] = *(const float2*)(Bx + base + (unsigned)(t0 + 16 + j) * D);
    }
#pragma unroll
    for (int j = 0; j < 8; ++j) { STEP2(Bf[j]); STORE2(t0 + 8 + j); }
    if (t0 + 24 < t_end) {
#pragma unroll
      for (int j = 0; j < 8; ++j) Bf[j] = *(const float2*)(Bx + base + (unsigned)(t0 + 24 + j) * D);
    }
  }
#undef STEP2
#undef STORE2
}

extern "C" void kernel_launch(void* const* d_in, const int* in_sizes, int n_in,
                              void* d_out, int out_size, void* d_ws, size_t ws_size,
                              hipStream_t stream) {
  const float* x  = (const float*)d_in[0];
  const float* Av = (const float*)d_in[1];
  const float* Bw = (const float*)d_in[2];
  const float* Wo = (const float*)d_in[3];
  const float* bo = (const float*)d_in[4];
  float* out = (float*)d_out;

  const int Bsz = 8, S = 2048, Din = 1024, Dst = 1024, Dout = 1024;
  const int M = Bsz * S;  // 16384

  char* ws = (char*)d_ws;
  unsigned short* x_bf  = (unsigned short*)ws;
  unsigned short* r_bf  = (unsigned short*)(ws + (size_t)M * Din * 2);
  unsigned short* Bw_bf = (unsigned short*)(ws + (size_t)M * Din * 4);
  unsigned short* Wo_bf = (unsigned short*)(ws + (size_t)M * Din * 4 + (size_t)Dst * Din * 2);
  float* dkc   = (float*)(ws + (size_t)M * Din * 4 + (size_t)Dst * Din * 4);
  float* bias2 = dkc + Dst;

  float* Bx = out;  // d_out doubles as pre-scan scratch (c'' values)

  { int n8 = M * Din / 8;
    cvt_f32_bf16<<<(n8 + 255) / 256, 256, 0, stream>>>(x, x_bf, 1.0f, n8); }
  { int n8 = Dst * Din / 8;
    cvt_f32_bf16<<<(n8 + 255) / 256, 256, 0, stream>>>(Bw, Bw_bf, 1.0f, n8); }
  { int n8 = Dout * Dst / 8;
    cvt_f32_bf16<<<(n8 + 255) / 256, 256, 0, stream>>>(Wo, Wo_bf, -2.0f, n8); }
  dkc_kernel<<<4, 256, 0, stream>>>(Av, dkc, Dst);
  bias2_kernel<<<Dout / 4, 256, 0, stream>>>(Wo, bo, bias2);

  gemm256<0><<<dim3((M / 256) * (Dst / 256)), 512, 0, stream>>>(x_bf, Bw_bf, Bx, dkc, M, Dst, Din);
  scan_kernel<<<dim3(128), 256, 0, stream>>>(Bx, Av, r_bf);
  gemm256<1><<<dim3((M / 256) * (Dout / 256)), 512, 0, stream>>>(r_bf, Wo_bf, out, bias2, M, Dout, Dst);
}